// Round 9
// baseline (403.795 us; speedup 1.0000x reference)
//
#include <hip/hip_runtime.h>
#include <hip/hip_bf16.h>
#include <hip/hip_cooperative_groups.h>
#include <math.h>

namespace cg = cooperative_groups;

typedef short bf16x8 __attribute__((ext_vector_type(8)));
typedef float f32x4 __attribute__((ext_vector_type(4)));

static __device__ __forceinline__ unsigned short f2bf(float f) {
    unsigned int u = __float_as_uint(f);
    unsigned int r = (u + 0x7fffu + ((u >> 16) & 1u)) >> 16;
    return (unsigned short)r;
}

// elementwise square of a bf16x8 fragment (bf16 -> f32 -> square -> bf16 rne)
static __device__ __forceinline__ bf16x8 sq_bf16x8(bf16x8 a) {
    bf16x8 r;
    #pragma unroll
    for (int i = 0; i < 8; ++i) {
        unsigned int u = ((unsigned int)(unsigned short)a[i]) << 16;
        float f = __uint_as_float(u);
        f *= f;
        r[i] = (short)f2bf(f);
    }
    return r;
}

static __device__ __forceinline__ float gelu_f(float x) {
    return 0.5f * x * (1.f + erff(x * 0.70710678118654752f));
}

// async global->LDS, 16B per lane; LDS dest is wave-uniform base + lane*16
static __device__ __forceinline__ void gload_lds16(const void* g, void* l) {
    __builtin_amdgcn_global_load_lds(
        (const __attribute__((address_space(1))) unsigned int*)g,
        (__attribute__((address_space(3))) unsigned int*)l, 16, 0, 0);
}

// LDS index skew for FFT buffers
static __device__ __forceinline__ int ldsmap(int i) { return i + (i >> 6); }

static __device__ __forceinline__ int rev4(int k) {
    int d0 = k % 10; k /= 10;
    int d1 = k % 10; k /= 10;
    int d2 = k % 10; int d3 = k / 10;
    return d0 * 1000 + d1 * 100 + d2 * 10 + d3;
}

// forward 5-point DFT (W5 = e^{-2pi i/5}), Winograd-style
static __device__ __forceinline__ void dft5(
    float a0r, float a0i, float a1r, float a1i, float a2r, float a2i,
    float a3r, float a3i, float a4r, float a4i,
    float* Xr, float* Xi)
{
    const float c1 = 0.30901699437494742f, c2 = -0.80901699437494745f;
    const float s1 = 0.95105651629515357f, s2 = 0.58778525229247312f;
    float t1r = a1r + a4r, t1i = a1i + a4i;
    float d1r = a1r - a4r, d1i = a1i - a4i;
    float t2r = a2r + a3r, t2i = a2i + a3i;
    float d2r = a2r - a3r, d2i = a2i - a3i;
    Xr[0] = a0r + t1r + t2r; Xi[0] = a0i + t1i + t2i;
    float m1r = a0r + c1 * t1r + c2 * t2r, m1i = a0i + c1 * t1i + c2 * t2i;
    float m2r = a0r + c2 * t1r + c1 * t2r, m2i = a0i + c2 * t1i + c1 * t2i;
    float n1r = s1 * d1r + s2 * d2r, n1i = s1 * d1i + s2 * d2i;
    float n2r = s2 * d1r - s1 * d2r, n2i = s2 * d1i - s1 * d2i;
    Xr[1] = m1r + n1i; Xi[1] = m1i - n1r;
    Xr[4] = m1r - n1i; Xi[4] = m1i + n1r;
    Xr[2] = m2r + n2i; Xi[2] = m2i - n2r;
    Xr[3] = m2r - n2i; Xi[3] = m2i + n2r;
}

// core of a radix-10 DIF butterfly given 10 loaded taps; writes LDS (twiddled)
// Self-contained twiddles (sincos + recurrence): r0/r2/r3 variants are equal
// clock-corrected, and this one needs NO init_tables launch.
template<int S>
static __device__ __forceinline__ void radix10_core(
    float* __restrict__ reb, float* __restrict__ imb,
    const float* ar, const float* ai, int base, int j)
{
    constexpr int L  = (S == 0) ? 1000 : (S == 1) ? 100 : (S == 2) ? 10 : 1;
    constexpr int SC = (S == 0) ? 1 : (S == 1) ? 10 : (S == 2) ? 100 : 1000;
    constexpr bool TW = (S != 3);

    const float WR[5] = {1.f, 0.80901699437494745f, 0.30901699437494742f,
                         -0.30901699437494742f, -0.80901699437494745f};
    const float WI[5] = {0.f, -0.58778525229247312f, -0.95105651629515357f,
                         -0.95105651629515357f, -0.58778525229247312f};

    float Er[5], Ei[5], Or[5], Oi[5];
    dft5(ar[0], ai[0], ar[2], ai[2], ar[4], ai[4], ar[6], ai[6], ar[8], ai[8], Er, Ei);
    dft5(ar[1], ai[1], ar[3], ai[3], ar[5], ai[5], ar[7], ai[7], ar[9], ai[9], Or, Oi);
    #pragma unroll
    for (int k = 1; k < 5; ++k) {
        float tr = Or[k] * WR[k] - Oi[k] * WI[k];
        Oi[k] = Or[k] * WI[k] + Oi[k] * WR[k];
        Or[k] = tr;
    }

    if (TW) {
        const float ang = (float)(j * SC) * -6.28318530717958648e-4f;
        float w1c, w1s;
        __sincosf(ang, &w1s, &w1c);
        float twr[10], twi[10];
        twr[0] = 1.f; twi[0] = 0.f;
        #pragma unroll
        for (int t = 1; t < 10; ++t) {
            twr[t] = twr[t - 1] * w1c - twi[t - 1] * w1s;
            twi[t] = twr[t - 1] * w1s + twi[t - 1] * w1c;
        }
        #pragma unroll
        for (int k = 0; k < 5; ++k) {
            float xr0 = Er[k] + Or[k], xi0 = Ei[k] + Oi[k];
            float xr1 = Er[k] - Or[k], xi1 = Ei[k] - Oi[k];
            int i0 = ldsmap(base + k * L);
            int i1 = ldsmap(base + (k + 5) * L);
            if (k == 0) {
                reb[i0] = xr0;
                imb[i0] = xi0;
            } else {
                reb[i0] = xr0 * twr[k] - xi0 * twi[k];
                imb[i0] = xr0 * twi[k] + xi0 * twr[k];
            }
            reb[i1] = xr1 * twr[k + 5] - xi1 * twi[k + 5];
            imb[i1] = xr1 * twi[k + 5] + xi1 * twr[k + 5];
        }
    } else {
        #pragma unroll
        for (int k = 0; k < 5; ++k) {
            int i0 = ldsmap(base + k * L);
            int i1 = ldsmap(base + (k + 5) * L);
            reb[i0] = Er[k] + Or[k]; imb[i0] = Ei[k] + Oi[k];
            reb[i1] = Er[k] - Or[k]; imb[i1] = Ei[k] - Oi[k];
        }
    }
}

// radix-10 DIF stage for S>=1 (reads LDS)
template<int S>
static __device__ __forceinline__ void radix10_stage(
    float* __restrict__ reb, float* __restrict__ imb, int tid)
{
    constexpr int L = (S == 1) ? 100 : (S == 2) ? 10 : 1;
    for (int w = tid; w < 1000; w += 512) {
        int g, j;
        if (S == 3) { g = w; j = 0; }
        else        { g = w / L; j = w - g * L; }
        const int base = g * (10 * L) + j;
        float ar[10], ai[10];
        #pragma unroll
        for (int u = 0; u < 10; ++u) {
            int idx = ldsmap(base + u * L);
            ar[u] = reb[idx];
            ai[u] = imb[idx];
        }
        radix10_core<S>(reb, imb, ar, ai, base, j);
    }
}

// ---------------------------------------------------------------------------
// Fused FFT + prep (r0-exact, self-contained: no table inputs -> no
// init_tables launch). Blocks [0,1024): FFT rows. Blocks [1024,3804): prep.
// ---------------------------------------------------------------------------
__global__ __launch_bounds__(512, 4)
void fft_prep_kernel(const float* __restrict__ x,
                     unsigned short* __restrict__ hb,
                     float* __restrict__ hnorm,
                     const float* __restrict__ W0, const float* __restrict__ A0,
                     unsigned short* __restrict__ Wb, unsigned short* __restrict__ Sb,
                     const float* __restrict__ W1, const float* __restrict__ A1,
                     const float* __restrict__ W2, const float* __restrict__ A2,
                     float* __restrict__ W1T, float* __restrict__ S1T,
                     float* __restrict__ W2T, float* __restrict__ S2T)
{
    if (blockIdx.x >= 1024) {
        // ---- prep path ----
        int idx = (blockIdx.x - 1024) * 512 + threadIdx.x;
        if (idx < 1280128) {
            const bool isW = idx < 640064;
            const int f4 = isW ? idx : idx - 640064;
            const float* src = isW ? W0 : A0;
            unsigned short* dst = isW ? Wb : Sb;
            float4 v = ((const float4*)src)[f4];
            float e[4] = {v.x, v.y, v.z, v.w};
            int flat = f4 * 4;
            int row = flat / 10001;
            int col = flat - row * 10001;
            #pragma unroll
            for (int i = 0; i < 4; ++i) {
                if (col == 10001) { row++; col = 0; }
                float val = isW ? e[i] : 1.f / (1.f + expf(-e[i]));
                dst[(size_t)row * 10240 + col] = f2bf(val);
                col++;
            }
        } else if (idx < 1341312) {
            int i = idx - 1280128;              // 256*239 pads
            int row = i / 239;
            int col = 10001 + (i - row * 239);
            Wb[(size_t)row * 10240 + col] = 0;
            Sb[(size_t)row * 10240 + col] = 0;
        } else if (idx < 1423232) {
            int o = idx - 1341312;              // 0..81919
            if (o < 32768) {
                int d = o >> 7, h = o & 127;
                W1T[o] = W1[h * 256 + d];
            } else if (o < 65536) {
                int p = o - 32768;
                int d = p >> 7, h = p & 127;
                S1T[p] = 1.f / (1.f + expf(-A1[h * 256 + d]));
            } else if (o < 73728) {
                int p = o - 65536;
                int d = p >> 6, h = p & 63;
                W2T[p] = W2[h * 128 + d];
            } else {
                int p = o - 73728;
                int d = p >> 6, h = p & 63;
                S2T[p] = 1.f / (1.f + expf(-A2[h * 128 + d]));
            }
        }
        return;
    }

    // ---- FFT path ----
    __shared__ float reb[10156];
    __shared__ float imb[10156];
    __shared__ float redbuf[8];

    const int b = blockIdx.x;
    const int tid = threadIdx.x;
    const int lane = tid & 63;
    const int wv = tid >> 6;

    // stage 0 fused with global load: z[n] = (x[2n], x[2n+1]) as float2
    const float2* z2 = (const float2*)(x + (size_t)b * 20000);
    for (int w = tid; w < 1000; w += 512) {
        float ar[10], ai[10];
        #pragma unroll
        for (int u = 0; u < 10; ++u) {
            float2 v = z2[w + u * 1000];
            ar[u] = v.x; ai[u] = v.y;
        }
        radix10_core<0>(reb, imb, ar, ai, w, w);
    }
    __syncthreads();
    radix10_stage<1>(reb, imb, tid);
    __syncthreads();
    radix10_stage<2>(reb, imb, tid);
    __syncthreads();
    radix10_stage<3>(reb, imb, tid);
    __syncthreads();

    // real-FFT untangle + log(1+|X|); h[0]=0 exactly (centered DC bin)
    float sumsq = 0.f;
    unsigned short* hrow = hb + (size_t)b * 10240;
    #pragma unroll
    for (int i = 0; i < 20; ++i) {
        int k = tid + i * 512;
        float hval = 0.f;
        if (k > 0 && k <= 10000) {
            int k1 = (k == 10000) ? 0 : k;
            int k2 = (k1 == 0) ? 0 : 10000 - k1;
            int i1 = ldsmap(rev4(k1));
            int i2 = ldsmap(rev4(k2));
            float zr = reb[i1], zi = imb[i1];
            float wr = reb[i2], wi = imb[i2];
            float er = 0.5f * (zr + wr);
            float ei = 0.5f * (zi - wi);
            float odr = 0.5f * (zi + wi);
            float odi = -0.5f * (zr - wr);
            float ct, st;
            __sincosf((float)k * -3.14159265358979324e-4f, &st, &ct);
            float xre = er + ct * odr - st * odi;
            float xim = ei + ct * odi + st * odr;
            hval = __logf(1.f + sqrtf(xre * xre + xim * xim));
        }
        hrow[k] = f2bf(hval);
        sumsq += hval * hval;
    }
    #pragma unroll
    for (int o = 32; o; o >>= 1) sumsq += __shfl_xor(sumsq, o);
    __syncthreads();
    if (lane == 0) redbuf[wv] = sumsq;
    __syncthreads();
    if (tid == 0) {
        float tsq = 0.f;
        #pragma unroll
        for (int i = 0; i < 8; ++i) tsq += redbuf[i];
        hnorm[b] = 1.f / (sqrtf(tsq) + 1e-8f);
    }
}

// ---------------------------------------------------------------------------
// FUSED gemm0 + combine_tail, cooperative launch (512 blocks x 256 thr,
// 2 blocks/CU co-resident). Phase A: r7's split-K=8 BM=64 dual GEMM (one
// z-slice per XCD). grid.sync(). Phase B: split-K reduce + 3-layer tail,
// 2 rows per block. Removes 2 launch boundaries (4 -> 2 dispatches total):
// ledger shows >=55us of dur_us is non-kernel overhead between launches.
// ---------------------------------------------------------------------------
__global__ __launch_bounds__(256, 2)
void gemm_tail_kernel(const unsigned short* __restrict__ hb,
                      const unsigned short* __restrict__ Wb, const unsigned short* __restrict__ Sb,
                      float* __restrict__ Py, float* __restrict__ Pp,
                      const float* __restrict__ hnorm,
                      const float* __restrict__ b0v, const float* __restrict__ eta0p,
                      const float* __restrict__ g0, const float* __restrict__ be0,
                      const float* __restrict__ W1T, const float* __restrict__ S1T,
                      const float* __restrict__ b1, const float* __restrict__ eta1p,
                      const float* __restrict__ g1, const float* __restrict__ be1,
                      const float* __restrict__ W2T, const float* __restrict__ S2T,
                      const float* __restrict__ b2, const float* __restrict__ eta2p,
                      const float* __restrict__ g2, const float* __restrict__ be2,
                      const float* __restrict__ hw, const float* __restrict__ hbod,
                      float* __restrict__ out)
{
    __shared__ unsigned short Ah[64 * 64];
    __shared__ unsigned short Bw[64 * 64];
    __shared__ unsigned short Bs[64 * 64];

    __shared__ float sh[2][256];
    __shared__ float sc[2][256];
    __shared__ float sv[2][128];
    __shared__ float sh2[2][128];
    __shared__ float sc2[2][128];
    __shared__ float sv2[2][64];
    __shared__ float p2a[2][2][64];
    __shared__ float p2b[2][2][64];
    __shared__ float redA[4][2];
    __shared__ float redB[4][2];

    const int t = threadIdx.x;
    const int lane = t & 63;
    const int wv = t >> 6;

    // ================= phase A: dual GEMM (r7-exact) =================
    {
        const int lin = blockIdx.x;           // 0..511
        const int z = lin & 7;                // 1 z-slice per XCD
        const int tile = lin >> 3;            // 0..63
        const int b0 = (tile & 15) * 64;
        const int n0 = (tile >> 4) * 64;

        const int ml = lane & 15;
        const int q4 = lane >> 4;
        const int s0 = q4 ^ (ml & 7);
        const int sub8 = lane >> 3;
        const int sl = lane & 7;
        const int gsw = sl ^ sub8;

        f32x4 accY[4], accP[4];
        #pragma unroll
        for (int nt = 0; nt < 4; ++nt) {
            accY[nt] = (f32x4){0.f, 0.f, 0.f, 0.f};
            accP[nt] = (f32x4){0.f, 0.f, 0.f, 0.f};
        }

        const int kbase = z * 1280;

        for (int step = 0; step < 20; ++step) {
            const int k0 = kbase + step * 64;
            __syncthreads();
            #pragma unroll
            for (int j = 0; j < 2; ++j) {
                const int c = wv * 2 + j;
                const size_t goA = (size_t)(b0 + c * 8 + sub8) * 10240 + k0 + gsw * 8;
                gload_lds16(&hb[goA], &Ah[c * 512]);
                const size_t goB = (size_t)(n0 + c * 8 + sub8) * 10240 + k0 + gsw * 8;
                gload_lds16(&Wb[goB], &Bw[c * 512]);
                gload_lds16(&Sb[goB], &Bs[c * 512]);
            }
            __syncthreads();

            #pragma unroll
            for (int kk = 0; kk < 2; ++kk) {
                const int slot = (s0 ^ (kk << 2)) << 3;
                bf16x8 ah, ac, bw[4], bs[4];
                const int mrow = wv * 16 + ml;
                ah = *(const bf16x8*)&Ah[mrow * 64 + slot];
                ac = sq_bf16x8(ah);
                #pragma unroll
                for (int nt = 0; nt < 4; ++nt) {
                    int nrow = nt * 16 + ml;
                    bw[nt] = *(const bf16x8*)&Bw[nrow * 64 + slot];
                    bs[nt] = *(const bf16x8*)&Bs[nrow * 64 + slot];
                }
                #pragma unroll
                for (int nt = 0; nt < 4; ++nt) {
                    accY[nt] = __builtin_amdgcn_mfma_f32_16x16x32_bf16(ah, bw[nt], accY[nt], 0, 0, 0);
                    accP[nt] = __builtin_amdgcn_mfma_f32_16x16x32_bf16(ac, bs[nt], accP[nt], 0, 0, 0);
                }
            }
        }

        const int rq = q4 * 4;
        #pragma unroll
        for (int nt = 0; nt < 4; ++nt)
            #pragma unroll
            for (int r = 0; r < 4; ++r) {
                int m = b0 + wv * 16 + rq + r;
                int n = n0 + nt * 16 + ml;
                size_t o = ((size_t)z * 1024 + m) * 256 + n;
                Py[o] = accY[nt][r];
                Pp[o] = accP[nt][r];
            }
    }

    // device-scope visibility of Py/Pp across XCDs, then grid barrier
    __threadfence();
    cg::this_grid().sync();

    // ================= phase B: combine + tail (r7-exact) =================
    {
        const int b0 = blockIdx.x * 2;

        const float e0 = eta0p[0];
        const float bias0 = b0v[t];
        float ys[2] = {0.f, 0.f}, ps[2] = {0.f, 0.f};
        #pragma unroll 4
        for (int s = 0; s < 8; ++s)
            #pragma unroll
            for (int r = 0; r < 2; ++r) {
                size_t o = ((size_t)s * 1024 + b0 + r) * 256 + t;
                ys[r] += Py[o];
                ps[r] += Pp[o];
            }
        float v[2];
        #pragma unroll
        for (int r = 0; r < 2; ++r) {
            float p = ps[r] * hnorm[b0 + r];
            float y = ys[r] + bias0;
            v[r] = y + e0 * tanhf(y) * p;
        }

        // LN(256) over columns, both rows in one barrier round
        float s1[2], s2[2];
        #pragma unroll
        for (int r = 0; r < 2; ++r) { s1[r] = v[r]; s2[r] = v[r] * v[r]; }
        #pragma unroll
        for (int o = 32; o; o >>= 1)
            #pragma unroll
            for (int r = 0; r < 2; ++r) { s1[r] += __shfl_xor(s1[r], o); s2[r] += __shfl_xor(s2[r], o); }
        if (lane == 0)
            #pragma unroll
            for (int r = 0; r < 2; ++r) { redA[wv][r] = s1[r]; redB[wv][r] = s2[r]; }
        __syncthreads();

        const float gg = g0[t], bb = be0[t];
        float gl[2], s3[2];
        #pragma unroll
        for (int r = 0; r < 2; ++r) {
            float sum = redA[0][r] + redA[1][r] + redA[2][r] + redA[3][r];
            float sumsq = redB[0][r] + redB[1][r] + redB[2][r] + redB[3][r];
            float mu = sum * (1.f / 256.f);
            float var = sumsq * (1.f / 256.f) - mu * mu;
            float u = (v[r] - mu) * rsqrtf(var + 1e-5f) * gg + bb;
            gl[r] = gelu_f(u);
            s3[r] = gl[r] * gl[r];
        }
        #pragma unroll
        for (int o = 32; o; o >>= 1)
            #pragma unroll
            for (int r = 0; r < 2; ++r) s3[r] += __shfl_xor(s3[r], o);
        __syncthreads();                 // redA reuse guard
        if (lane == 0)
            #pragma unroll
            for (int r = 0; r < 2; ++r) redA[wv][r] = s3[r];
        __syncthreads();
        #pragma unroll
        for (int r = 0; r < 2; ++r) {
            float gsq = redA[0][r] + redA[1][r] + redA[2][r] + redA[3][r];
            float inv = 1.f / (sqrtf(gsq) + 1e-8f);
            sh[r][t] = gl[r];
            sc[r][t] = gl[r] * gl[r] * inv;
        }
        __syncthreads();

        // ---- layer 1: 128 outputs x 2 rows ----
        const int hcol = t & 127;
        const int r1 = t >> 7;
        float ya = 0.f, pa = 0.f;
        #pragma unroll 8
        for (int d = 0; d < 256; ++d) {
            ya += sh[r1][d] * W1T[d * 128 + hcol];
            pa += sc[r1][d] * S1T[d * 128 + hcol];
        }
        {
            const float e1 = eta1p[0];
            float y = ya + b1[hcol];
            sv[r1][hcol] = y + e1 * tanhf(y) * pa;
        }
        __syncthreads();

        // LN(128) + gelu + c2: wave per row (waves 0,1)
        if (wv < 2) {
            int r = wv;
            float v0 = sv[r][lane];
            float v1 = sv[r][lane + 64];
            float s = v0 + v1, sq = v0 * v0 + v1 * v1;
            #pragma unroll
            for (int o = 32; o; o >>= 1) { s += __shfl_xor(s, o); sq += __shfl_xor(sq, o); }
            float mu = s * (1.f / 128.f);
            float var = sq * (1.f / 128.f) - mu * mu;
            float rs = rsqrtf(var + 1e-5f);
            float u0 = (v0 - mu) * rs * g1[lane] + be1[lane];
            float u1 = (v1 - mu) * rs * g1[lane + 64] + be1[lane + 64];
            float ge0 = gelu_f(u0);
            float ge1 = gelu_f(u1);
            float gsq = ge0 * ge0 + ge1 * ge1;
            #pragma unroll
            for (int o = 32; o; o >>= 1) gsq += __shfl_xor(gsq, o);
            float inv = 1.f / (sqrtf(gsq) + 1e-8f);
            sh2[r][lane] = ge0; sh2[r][lane + 64] = ge1;
            sc2[r][lane] = ge0 * ge0 * inv; sc2[r][lane + 64] = ge1 * ge1 * inv;
        }
        __syncthreads();

        // ---- layer 2: 64 outputs x 2 rows, d-dim split across 2 halves ----
        {
            const int h2c = t & 63;
            const int r = (t >> 6) & 1;
            const int dh = t >> 7;
            float yb = 0.f, pb = 0.f;
            #pragma unroll 8
            for (int dd = 0; dd < 64; ++dd) {
                int d = dh * 64 + dd;
                yb += sh2[r][d] * W2T[d * 64 + h2c];
                pb += sc2[r][d] * S2T[d * 64 + h2c];
            }
            p2a[dh][r][h2c] = yb;
            p2b[dh][r][h2c] = pb;
        }
        __syncthreads();
        if (t < 128) {
            const int h2c = t & 63;
            const int r = t >> 6;
            const float e2 = eta2p[0];
            float yb = p2a[0][r][h2c] + p2a[1][r][h2c];
            float pb = p2b[0][r][h2c] + p2b[1][r][h2c];
            float y = yb + b2[h2c];
            sv2[r][h2c] = y + e2 * tanhf(y) * pb;
        }
        __syncthreads();

        // LN(64) + gelu + head: wave per row (waves 0,1)
        if (wv < 2) {
            int r = wv;
            float v0 = sv2[r][lane];
            float s = v0, sq = v0 * v0;
            #pragma unroll
            for (int o = 32; o; o >>= 1) { s += __shfl_xor(s, o); sq += __shfl_xor(sq, o); }
            float mu = s * (1.f / 64.f);
            float var = sq * (1.f / 64.f) - mu * mu;
            float rs = rsqrtf(var + 1e-5f);
            float u = (v0 - mu) * rs * g2[lane] + be2[lane];
            float g = gelu_f(u);
            float hc = g * hw[lane];
            #pragma unroll
            for (int o = 32; o; o >>= 1) hc += __shfl_xor(hc, o);
            if (lane == 0) out[b0 + r] = hc + hbod[0];
        }
    }
}

// ---------------------------------------------------------------------------
extern "C" void kernel_launch(void* const* d_in, const int* in_sizes, int n_in,
                              void* d_out, int out_size, void* d_ws, size_t ws_size,
                              hipStream_t stream)
{
    const float* x    = (const float*)d_in[0];
    const float* W0   = (const float*)d_in[1];
    const float* A0   = (const float*)d_in[2];
    const float* b0   = (const float*)d_in[3];
    const float* eta0 = (const float*)d_in[4];
    const float* g0   = (const float*)d_in[5];
    const float* be0  = (const float*)d_in[6];
    const float* W1   = (const float*)d_in[7];
    const float* A1   = (const float*)d_in[8];
    const float* b1   = (const float*)d_in[9];
    const float* eta1 = (const float*)d_in[10];
    const float* g1   = (const float*)d_in[11];
    const float* be1  = (const float*)d_in[12];
    const float* W2   = (const float*)d_in[13];
    const float* A2   = (const float*)d_in[14];
    const float* b2   = (const float*)d_in[15];
    const float* eta2 = (const float*)d_in[16];
    const float* g2   = (const float*)d_in[17];
    const float* be2  = (const float*)d_in[18];
    const float* hw   = (const float*)d_in[19];
    const float* hbod = (const float*)d_in[20];
    float* out = (float*)d_out;

    char* w = (char*)d_ws;
    unsigned short* hb  = (unsigned short*)(w + 0);          // 20971520
    unsigned short* Wb0 = (unsigned short*)(w + 20971520);   // 5242880
    unsigned short* Sb0 = (unsigned short*)(w + 26214400);   // 5242880
    float* Py   = (float*)(w + 31457280);                    // 8388608
    float* Pp   = (float*)(w + 39845888);                    // 8388608
    float* W1T  = (float*)(w + 48234496);                    // 131072
    float* S1T  = (float*)(w + 48365568);                    // 131072
    float* W2T  = (float*)(w + 48496640);                    // 32768
    float* S2T  = (float*)(w + 48529408);                    // 32768
    float* hnm  = (float*)(w + 48562176);                    // 4096
    // total = 48566272 bytes

    hipLaunchKernelGGL(fft_prep_kernel, dim3(3804), dim3(512), 0, stream,
                       x, hb, hnm, W0, A0, Wb0, Sb0, W1, A1, W2, A2, W1T, S1T, W2T, S2T);

    void* kargs[] = {
        (void*)&hb, (void*)&Wb0, (void*)&Sb0, (void*)&Py, (void*)&Pp,
        (void*)&hnm,
        (void*)&b0, (void*)&eta0, (void*)&g0, (void*)&be0,
        (void*)&W1T, (void*)&S1T, (void*)&b1, (void*)&eta1,
        (void*)&g1, (void*)&be1, (void*)&W2T, (void*)&S2T,
        (void*)&b2, (void*)&eta2, (void*)&g2, (void*)&be2,
        (void*)&hw, (void*)&hbod, (void*)&out
    };
    hipLaunchCooperativeKernel(reinterpret_cast<void*>(gemm_tail_kernel),
                               dim3(512), dim3(256), kargs, 0, stream);
}

// Round 10
// 249.942 us; speedup vs baseline: 1.6156x; 1.6156x over previous
//
#include <hip/hip_runtime.h>
#include <hip/hip_bf16.h>
#include <math.h>

typedef short bf16x8 __attribute__((ext_vector_type(8)));
typedef float f32x4 __attribute__((ext_vector_type(4)));

static __device__ __forceinline__ unsigned short f2bf(float f) {
    unsigned int u = __float_as_uint(f);
    unsigned int r = (u + 0x7fffu + ((u >> 16) & 1u)) >> 16;
    return (unsigned short)r;
}

// elementwise square of a bf16x8 fragment (bf16 -> f32 -> square -> bf16 rne)
static __device__ __forceinline__ bf16x8 sq_bf16x8(bf16x8 a) {
    bf16x8 r;
    #pragma unroll
    for (int i = 0; i < 8; ++i) {
        unsigned int u = ((unsigned int)(unsigned short)a[i]) << 16;
        float f = __uint_as_float(u);
        f *= f;
        r[i] = (short)f2bf(f);
    }
    return r;
}

static __device__ __forceinline__ float gelu_f(float x) {
    return 0.5f * x * (1.f + erff(x * 0.70710678118654752f));
}

// async global->LDS, 16B per lane; LDS dest is wave-uniform base + lane*16
static __device__ __forceinline__ void gload_lds16(const void* g, void* l) {
    __builtin_amdgcn_global_load_lds(
        (const __attribute__((address_space(1))) unsigned int*)g,
        (__attribute__((address_space(3))) unsigned int*)l, 16, 0, 0);
}

// LDS index skew for FFT buffers
static __device__ __forceinline__ int ldsmap(int i) { return i + (i >> 6); }

static __device__ __forceinline__ int rev4(int k) {
    int d0 = k % 10; k /= 10;
    int d1 = k % 10; k /= 10;
    int d2 = k % 10; int d3 = k / 10;
    return d0 * 1000 + d1 * 100 + d2 * 10 + d3;
}

// forward 5-point DFT (W5 = e^{-2pi i/5}), Winograd-style
static __device__ __forceinline__ void dft5(
    float a0r, float a0i, float a1r, float a1i, float a2r, float a2i,
    float a3r, float a3i, float a4r, float a4i,
    float* Xr, float* Xi)
{
    const float c1 = 0.30901699437494742f, c2 = -0.80901699437494745f;
    const float s1 = 0.95105651629515357f, s2 = 0.58778525229247312f;
    float t1r = a1r + a4r, t1i = a1i + a4i;
    float d1r = a1r - a4r, d1i = a1i - a4i;
    float t2r = a2r + a3r, t2i = a2i + a3i;
    float d2r = a2r - a3r, d2i = a2i - a3i;
    Xr[0] = a0r + t1r + t2r; Xi[0] = a0i + t1i + t2i;
    float m1r = a0r + c1 * t1r + c2 * t2r, m1i = a0i + c1 * t1i + c2 * t2i;
    float m2r = a0r + c2 * t1r + c1 * t2r, m2i = a0i + c2 * t1i + c1 * t2i;
    float n1r = s1 * d1r + s2 * d2r, n1i = s1 * d1i + s2 * d2i;
    float n2r = s2 * d1r - s1 * d2r, n2i = s2 * d1i - s1 * d2i;
    Xr[1] = m1r + n1i; Xi[1] = m1i - n1r;
    Xr[4] = m1r - n1i; Xi[4] = m1i + n1r;
    Xr[2] = m2r + n2i; Xi[2] = m2i - n2r;
    Xr[3] = m2r - n2i; Xi[3] = m2i + n2r;
}

// core of a radix-10 DIF butterfly given 10 loaded taps; writes LDS (twiddled)
// Self-contained twiddles (sincos + recurrence): equal to the table variants
// clock-corrected, and needs NO init_tables launch.
template<int S>
static __device__ __forceinline__ void radix10_core(
    float* __restrict__ reb, float* __restrict__ imb,
    const float* ar, const float* ai, int base, int j)
{
    constexpr int L  = (S == 0) ? 1000 : (S == 1) ? 100 : (S == 2) ? 10 : 1;
    constexpr int SC = (S == 0) ? 1 : (S == 1) ? 10 : (S == 2) ? 100 : 1000;
    constexpr bool TW = (S != 3);

    const float WR[5] = {1.f, 0.80901699437494745f, 0.30901699437494742f,
                         -0.30901699437494742f, -0.80901699437494745f};
    const float WI[5] = {0.f, -0.58778525229247312f, -0.95105651629515357f,
                         -0.95105651629515357f, -0.58778525229247312f};

    float Er[5], Ei[5], Or[5], Oi[5];
    dft5(ar[0], ai[0], ar[2], ai[2], ar[4], ai[4], ar[6], ai[6], ar[8], ai[8], Er, Ei);
    dft5(ar[1], ai[1], ar[3], ai[3], ar[5], ai[5], ar[7], ai[7], ar[9], ai[9], Or, Oi);
    #pragma unroll
    for (int k = 1; k < 5; ++k) {
        float tr = Or[k] * WR[k] - Oi[k] * WI[k];
        Oi[k] = Or[k] * WI[k] + Oi[k] * WR[k];
        Or[k] = tr;
    }

    if (TW) {
        const float ang = (float)(j * SC) * -6.28318530717958648e-4f;
        float w1c, w1s;
        __sincosf(ang, &w1s, &w1c);
        float twr[10], twi[10];
        twr[0] = 1.f; twi[0] = 0.f;
        #pragma unroll
        for (int t = 1; t < 10; ++t) {
            twr[t] = twr[t - 1] * w1c - twi[t - 1] * w1s;
            twi[t] = twr[t - 1] * w1s + twi[t - 1] * w1c;
        }
        #pragma unroll
        for (int k = 0; k < 5; ++k) {
            float xr0 = Er[k] + Or[k], xi0 = Ei[k] + Oi[k];
            float xr1 = Er[k] - Or[k], xi1 = Ei[k] - Oi[k];
            int i0 = ldsmap(base + k * L);
            int i1 = ldsmap(base + (k + 5) * L);
            if (k == 0) {
                reb[i0] = xr0;
                imb[i0] = xi0;
            } else {
                reb[i0] = xr0 * twr[k] - xi0 * twi[k];
                imb[i0] = xr0 * twi[k] + xi0 * twr[k];
            }
            reb[i1] = xr1 * twr[k + 5] - xi1 * twi[k + 5];
            imb[i1] = xr1 * twi[k + 5] + xi1 * twr[k + 5];
        }
    } else {
        #pragma unroll
        for (int k = 0; k < 5; ++k) {
            int i0 = ldsmap(base + k * L);
            int i1 = ldsmap(base + (k + 5) * L);
            reb[i0] = Er[k] + Or[k]; imb[i0] = Ei[k] + Oi[k];
            reb[i1] = Er[k] - Or[k]; imb[i1] = Ei[k] - Oi[k];
        }
    }
}

// radix-10 DIF stage for S>=1 (reads LDS)
template<int S>
static __device__ __forceinline__ void radix10_stage(
    float* __restrict__ reb, float* __restrict__ imb, int tid)
{
    constexpr int L = (S == 1) ? 100 : (S == 2) ? 10 : 1;
    for (int w = tid; w < 1000; w += 512) {
        int g, j;
        if (S == 3) { g = w; j = 0; }
        else        { g = w / L; j = w - g * L; }
        const int base = g * (10 * L) + j;
        float ar[10], ai[10];
        #pragma unroll
        for (int u = 0; u < 10; ++u) {
            int idx = ldsmap(base + u * L);
            ar[u] = reb[idx];
            ai[u] = imb[idx];
        }
        radix10_core<S>(reb, imb, ar, ai, base, j);
    }
}

// ---------------------------------------------------------------------------
// Fused FFT + prep (r0-exact, self-contained). Blocks [0,1024): FFT rows.
// Blocks [1024,3804): weight prep.
// ---------------------------------------------------------------------------
__global__ __launch_bounds__(512, 4)
void fft_prep_kernel(const float* __restrict__ x,
                     unsigned short* __restrict__ hb,
                     float* __restrict__ hnorm,
                     const float* __restrict__ W0, const float* __restrict__ A0,
                     unsigned short* __restrict__ Wb, unsigned short* __restrict__ Sb,
                     const float* __restrict__ W1, const float* __restrict__ A1,
                     const float* __restrict__ W2, const float* __restrict__ A2,
                     float* __restrict__ W1T, float* __restrict__ S1T,
                     float* __restrict__ W2T, float* __restrict__ S2T)
{
    if (blockIdx.x >= 1024) {
        // ---- prep path ----
        int idx = (blockIdx.x - 1024) * 512 + threadIdx.x;
        if (idx < 1280128) {
            const bool isW = idx < 640064;
            const int f4 = isW ? idx : idx - 640064;
            const float* src = isW ? W0 : A0;
            unsigned short* dst = isW ? Wb : Sb;
            float4 v = ((const float4*)src)[f4];
            float e[4] = {v.x, v.y, v.z, v.w};
            int flat = f4 * 4;
            int row = flat / 10001;
            int col = flat - row * 10001;
            #pragma unroll
            for (int i = 0; i < 4; ++i) {
                if (col == 10001) { row++; col = 0; }
                float val = isW ? e[i] : 1.f / (1.f + expf(-e[i]));
                dst[(size_t)row * 10240 + col] = f2bf(val);
                col++;
            }
        } else if (idx < 1341312) {
            int i = idx - 1280128;              // 256*239 pads
            int row = i / 239;
            int col = 10001 + (i - row * 239);
            Wb[(size_t)row * 10240 + col] = 0;
            Sb[(size_t)row * 10240 + col] = 0;
        } else if (idx < 1423232) {
            int o = idx - 1341312;              // 0..81919
            if (o < 32768) {
                int d = o >> 7, h = o & 127;
                W1T[o] = W1[h * 256 + d];
            } else if (o < 65536) {
                int p = o - 32768;
                int d = p >> 7, h = p & 127;
                S1T[p] = 1.f / (1.f + expf(-A1[h * 256 + d]));
            } else if (o < 73728) {
                int p = o - 65536;
                int d = p >> 6, h = p & 63;
                W2T[p] = W2[h * 128 + d];
            } else {
                int p = o - 73728;
                int d = p >> 6, h = p & 63;
                S2T[p] = 1.f / (1.f + expf(-A2[h * 128 + d]));
            }
        }
        return;
    }

    // ---- FFT path ----
    __shared__ float reb[10156];
    __shared__ float imb[10156];
    __shared__ float redbuf[8];

    const int b = blockIdx.x;
    const int tid = threadIdx.x;
    const int lane = tid & 63;
    const int wv = tid >> 6;

    // stage 0 fused with global load: z[n] = (x[2n], x[2n+1]) as float2
    const float2* z2 = (const float2*)(x + (size_t)b * 20000);
    for (int w = tid; w < 1000; w += 512) {
        float ar[10], ai[10];
        #pragma unroll
        for (int u = 0; u < 10; ++u) {
            float2 v = z2[w + u * 1000];
            ar[u] = v.x; ai[u] = v.y;
        }
        radix10_core<0>(reb, imb, ar, ai, w, w);
    }
    __syncthreads();
    radix10_stage<1>(reb, imb, tid);
    __syncthreads();
    radix10_stage<2>(reb, imb, tid);
    __syncthreads();
    radix10_stage<3>(reb, imb, tid);
    __syncthreads();

    // real-FFT untangle + log(1+|X|); h[0]=0 exactly (centered DC bin)
    float sumsq = 0.f;
    unsigned short* hrow = hb + (size_t)b * 10240;
    #pragma unroll
    for (int i = 0; i < 20; ++i) {
        int k = tid + i * 512;
        float hval = 0.f;
        if (k > 0 && k <= 10000) {
            int k1 = (k == 10000) ? 0 : k;
            int k2 = (k1 == 0) ? 0 : 10000 - k1;
            int i1 = ldsmap(rev4(k1));
            int i2 = ldsmap(rev4(k2));
            float zr = reb[i1], zi = imb[i1];
            float wr = reb[i2], wi = imb[i2];
            float er = 0.5f * (zr + wr);
            float ei = 0.5f * (zi - wi);
            float odr = 0.5f * (zi + wi);
            float odi = -0.5f * (zr - wr);
            float ct, st;
            __sincosf((float)k * -3.14159265358979324e-4f, &st, &ct);
            float xre = er + ct * odr - st * odi;
            float xim = ei + ct * odi + st * odr;
            hval = __logf(1.f + sqrtf(xre * xre + xim * xim));
        }
        hrow[k] = f2bf(hval);
        sumsq += hval * hval;
    }
    #pragma unroll
    for (int o = 32; o; o >>= 1) sumsq += __shfl_xor(sumsq, o);
    __syncthreads();
    if (lane == 0) redbuf[wv] = sumsq;
    __syncthreads();
    if (tid == 0) {
        float tsq = 0.f;
        #pragma unroll
        for (int i = 0; i < 8; ++i) tsq += redbuf[i];
        hnorm[b] = 1.f / (sqrtf(tsq) + 1e-8f);
    }
}

// ---------------------------------------------------------------------------
// Layer-0 dual GEMM, split-K=8, BM=64 BN=64 BK=64, one z-slice per XCD.
// r10: T4 counted-vmcnt pipeline. r9's fused counters proved this kernel
// class is >90% stall (MfmaUtil 2.5%, VALU 7%, HBM 3%); r8's dbuf failed
// because __syncthreads drains vmcnt(0) (T3-without-T4 = nothing, m218).
// Here: 2-deep stage pipeline, raw s_barrier, per-wave s_waitcnt vmcnt(6)
// (never 0 until the last step), sched_barrier(0) fences per rule #18.
// Invariants: barrier-1 reached only after own tile-s loads landed (all
// waves -> tile complete); barrier-2 (sched-pinned after compute) ensures
// no wave restages a buffer still being read. LDS 48KB -> 3 blocks/CU.
// ---------------------------------------------------------------------------
__global__ __launch_bounds__(256, 3)
void gemm0_kernel(const unsigned short* __restrict__ hb,
                  const unsigned short* __restrict__ Wb, const unsigned short* __restrict__ Sb,
                  float* __restrict__ Py, float* __restrict__ Pp)
{
    __shared__ unsigned short Ah[2][64 * 64];
    __shared__ unsigned short Bw[2][64 * 64];
    __shared__ unsigned short Bs[2][64 * 64];

    const int t = threadIdx.x;
    const int lin = blockIdx.x;           // 0..511
    const int z = lin & 7;                // 1 z-slice per XCD (round-robin)
    const int tile = lin >> 3;            // 0..63
    const int b0 = (tile & 15) * 64;
    const int n0 = (tile >> 4) * 64;

    const int lane = t & 63;
    const int wv = t >> 6;
    const int ml = lane & 15;
    const int q4 = lane >> 4;
    const int s0 = q4 ^ (ml & 7);

    const int sub8 = lane >> 3;
    const int sl = lane & 7;
    const int gsw = sl ^ sub8;

    f32x4 accY[4], accP[4];
    #pragma unroll
    for (int nt = 0; nt < 4; ++nt) {
        accY[nt] = (f32x4){0.f, 0.f, 0.f, 0.f};
        accP[nt] = (f32x4){0.f, 0.f, 0.f, 0.f};
    }

    const int kbase = z * 1280;

    auto STAGE = [&](int buf, int step) {
        const int k0 = kbase + step * 64;
        #pragma unroll
        for (int j = 0; j < 2; ++j) {
            const int c = wv * 2 + j;     // rows c*8..c*8+7
            const size_t goA = (size_t)(b0 + c * 8 + sub8) * 10240 + k0 + gsw * 8;
            gload_lds16(&hb[goA], &Ah[buf][c * 512]);
            const size_t goB = (size_t)(n0 + c * 8 + sub8) * 10240 + k0 + gsw * 8;
            gload_lds16(&Wb[goB], &Bw[buf][c * 512]);
            gload_lds16(&Sb[goB], &Bs[buf][c * 512]);
        }
    };

    // prologue: 2 tiles in flight (12 outstanding VMEM per thread)
    STAGE(0, 0);
    STAGE(1, 1);

    for (int step = 0; step < 20; ++step) {
        const int cur = step & 1;
        // wait MY tile-step loads (oldest 6); newer 6 stay in flight
        if (step == 19) { asm volatile("s_waitcnt vmcnt(0)" ::: "memory"); }
        else            { asm volatile("s_waitcnt vmcnt(6)" ::: "memory"); }
        __builtin_amdgcn_sched_barrier(0);
        __builtin_amdgcn_s_barrier();     // all waves' tile-step loads landed

        #pragma unroll
        for (int kk = 0; kk < 2; ++kk) {
            const int slot = (s0 ^ (kk << 2)) << 3;
            bf16x8 ah, ac, bw[4], bs[4];
            const int mrow = wv * 16 + ml;
            ah = *(const bf16x8*)&Ah[cur][mrow * 64 + slot];
            ac = sq_bf16x8(ah);
            #pragma unroll
            for (int nt = 0; nt < 4; ++nt) {
                int nrow = nt * 16 + ml;
                bw[nt] = *(const bf16x8*)&Bw[cur][nrow * 64 + slot];
                bs[nt] = *(const bf16x8*)&Bs[cur][nrow * 64 + slot];
            }
            #pragma unroll
            for (int nt = 0; nt < 4; ++nt) {
                accY[nt] = __builtin_amdgcn_mfma_f32_16x16x32_bf16(ah, bw[nt], accY[nt], 0, 0, 0);
                accP[nt] = __builtin_amdgcn_mfma_f32_16x16x32_bf16(ac, bs[nt], accP[nt], 0, 0, 0);
            }
        }

        __builtin_amdgcn_sched_barrier(0); // pin compute (ds_reads consumed) above
        __builtin_amdgcn_s_barrier();      // all waves done reading buf[cur]
        if (step + 2 < 20) STAGE(cur, step + 2);   // restage -> 12 in flight
    }

    const int rq = q4 * 4;
    #pragma unroll
    for (int nt = 0; nt < 4; ++nt)
        #pragma unroll
        for (int r = 0; r < 4; ++r) {
            int m = b0 + wv * 16 + rq + r;
            int n = n0 + nt * 16 + ml;
            size_t o = ((size_t)z * 1024 + m) * 256 + n;
            Py[o] = accY[nt][r];
            Pp[o] = accP[nt][r];
        }
}

// ---------------------------------------------------------------------------
// Fused combine + tail: split-K(8) reduce + layer-0 plastic/LN/GELU (in LDS),
// then layers 1,2 + head. 2 rows per block, grid 512 x 256 thr.
// ---------------------------------------------------------------------------
__global__ __launch_bounds__(256)
void combine_tail_kernel(const float* __restrict__ Py, const float* __restrict__ Pp,
                 const float* __restrict__ hnorm,
                 const float* __restrict__ b0v, const float* __restrict__ eta0p,
                 const float* __restrict__ g0, const float* __restrict__ be0,
                 const float* __restrict__ W1T, const float* __restrict__ S1T,
                 const float* __restrict__ b1, const float* __restrict__ eta1p,
                 const float* __restrict__ g1, const float* __restrict__ be1,
                 const float* __restrict__ W2T, const float* __restrict__ S2T,
                 const float* __restrict__ b2, const float* __restrict__ eta2p,
                 const float* __restrict__ g2, const float* __restrict__ be2,
                 const float* __restrict__ hw, const float* __restrict__ hbod,
                 float* __restrict__ out)
{
    __shared__ float sh[2][256];
    __shared__ float sc[2][256];
    __shared__ float sv[2][128];
    __shared__ float sh2[2][128];
    __shared__ float sc2[2][128];
    __shared__ float sv2[2][64];
    __shared__ float p2a[2][2][64];  // [dhalf][row][h2]
    __shared__ float p2b[2][2][64];
    __shared__ float redA[4][2];     // [wave][row]
    __shared__ float redB[4][2];

    const int t = threadIdx.x;       // column 0..255
    const int b0 = blockIdx.x * 2;
    const int lane = t & 63;
    const int wv = t >> 6;

    // ---- combine phase: split-K reduce + plastic for 2 rows ----
    const float e0 = eta0p[0];
    const float bias0 = b0v[t];
    float ys[2] = {0.f, 0.f}, ps[2] = {0.f, 0.f};
    #pragma unroll 4
    for (int s = 0; s < 8; ++s)
        #pragma unroll
        for (int r = 0; r < 2; ++r) {
            size_t o = ((size_t)s * 1024 + b0 + r) * 256 + t;
            ys[r] += Py[o];
            ps[r] += Pp[o];
        }
    float v[2];
    #pragma unroll
    for (int r = 0; r < 2; ++r) {
        float p = ps[r] * hnorm[b0 + r];
        float y = ys[r] + bias0;
        v[r] = y + e0 * tanhf(y) * p;
    }

    // LN(256) over columns, both rows in one barrier round
    float s1[2], s2[2];
    #pragma unroll
    for (int r = 0; r < 2; ++r) { s1[r] = v[r]; s2[r] = v[r] * v[r]; }
    #pragma unroll
    for (int o = 32; o; o >>= 1)
        #pragma unroll
        for (int r = 0; r < 2; ++r) { s1[r] += __shfl_xor(s1[r], o); s2[r] += __shfl_xor(s2[r], o); }
    if (lane == 0)
        #pragma unroll
        for (int r = 0; r < 2; ++r) { redA[wv][r] = s1[r]; redB[wv][r] = s2[r]; }
    __syncthreads();

    const float gg = g0[t], bb = be0[t];
    float gl[2], s3[2];
    #pragma unroll
    for (int r = 0; r < 2; ++r) {
        float sum = redA[0][r] + redA[1][r] + redA[2][r] + redA[3][r];
        float sumsq = redB[0][r] + redB[1][r] + redB[2][r] + redB[3][r];
        float mu = sum * (1.f / 256.f);
        float var = sumsq * (1.f / 256.f) - mu * mu;
        float u = (v[r] - mu) * rsqrtf(var + 1e-5f) * gg + bb;
        gl[r] = gelu_f(u);
        s3[r] = gl[r] * gl[r];
    }
    #pragma unroll
    for (int o = 32; o; o >>= 1)
        #pragma unroll
        for (int r = 0; r < 2; ++r) s3[r] += __shfl_xor(s3[r], o);
    __syncthreads();                 // redA reuse guard
    if (lane == 0)
        #pragma unroll
        for (int r = 0; r < 2; ++r) redA[wv][r] = s3[r];
    __syncthreads();
    #pragma unroll
    for (int r = 0; r < 2; ++r) {
        float gsq = redA[0][r] + redA[1][r] + redA[2][r] + redA[3][r];
        float inv = 1.f / (sqrtf(gsq) + 1e-8f);
        sh[r][t] = gl[r];
        sc[r][t] = gl[r] * gl[r] * inv;
    }
    __syncthreads();

    // ---- layer 1: 128 outputs x 2 rows; one (row, col) per thread ----
    const int hcol = t & 127;
    const int r1 = t >> 7;           // 0..1
    float ya = 0.f, pa = 0.f;
    #pragma unroll 8
    for (int d = 0; d < 256; ++d) {
        ya += sh[r1][d] * W1T[d * 128 + hcol];
        pa += sc[r1][d] * S1T[d * 128 + hcol];
    }
    {
        const float e1 = eta1p[0];
        float y = ya + b1[hcol];
        sv[r1][hcol] = y + e1 * tanhf(y) * pa;
    }
    __syncthreads();

    // LN(128) + gelu + c2: wave per row (waves 0,1)
    if (wv < 2) {
        int r = wv;
        float v0 = sv[r][lane];
        float v1 = sv[r][lane + 64];
        float s = v0 + v1, sq = v0 * v0 + v1 * v1;
        #pragma unroll
        for (int o = 32; o; o >>= 1) { s += __shfl_xor(s, o); sq += __shfl_xor(sq, o); }
        float mu = s * (1.f / 128.f);
        float var = sq * (1.f / 128.f) - mu * mu;
        float rs = rsqrtf(var + 1e-5f);
        float u0 = (v0 - mu) * rs * g1[lane] + be1[lane];
        float u1 = (v1 - mu) * rs * g1[lane + 64] + be1[lane + 64];
        float ge0 = gelu_f(u0);
        float ge1 = gelu_f(u1);
        float gsq = ge0 * ge0 + ge1 * ge1;
        #pragma unroll
        for (int o = 32; o; o >>= 1) gsq += __shfl_xor(gsq, o);
        float inv = 1.f / (sqrtf(gsq) + 1e-8f);
        sh2[r][lane] = ge0; sh2[r][lane + 64] = ge1;
        sc2[r][lane] = ge0 * ge0 * inv; sc2[r][lane + 64] = ge1 * ge1 * inv;
    }
    __syncthreads();

    // ---- layer 2: 64 outputs x 2 rows, d-dim split across 2 halves ----
    {
        const int h2c = t & 63;
        const int r = (t >> 6) & 1;
        const int dh = t >> 7;       // 0..1
        float yb = 0.f, pb = 0.f;
        #pragma unroll 8
        for (int dd = 0; dd < 64; ++dd) {
            int d = dh * 64 + dd;
            yb += sh2[r][d] * W2T[d * 64 + h2c];
            pb += sc2[r][d] * S2T[d * 64 + h2c];
        }
        p2a[dh][r][h2c] = yb;
        p2b[dh][r][h2c] = pb;
    }
    __syncthreads();
    if (t < 128) {
        const int h2c = t & 63;
        const int r = t >> 6;
        const float e2 = eta2p[0];
        float yb = p2a[0][r][h2c] + p2a[1][r][h2c];
        float pb = p2b[0][r][h2c] + p2b[1][r][h2c];
        float y = yb + b2[h2c];
        sv2[r][h2c] = y + e2 * tanhf(y) * pb;
    }
    __syncthreads();

    // LN(64) + gelu + head: wave per row (waves 0,1)
    if (wv < 2) {
        int r = wv;
        float v0 = sv2[r][lane];
        float s = v0, sq = v0 * v0;
        #pragma unroll
        for (int o = 32; o; o >>= 1) { s += __shfl_xor(s, o); sq += __shfl_xor(sq, o); }
        float mu = s * (1.f / 64.f);
        float var = sq * (1.f / 64.f) - mu * mu;
        float rs = rsqrtf(var + 1e-5f);
        float u = (v0 - mu) * rs * g2[lane] + be2[lane];
        float g = gelu_f(u);
        float hc = g * hw[lane];
        #pragma unroll
        for (int o = 32; o; o >>= 1) hc += __shfl_xor(hc, o);
        if (lane == 0) out[b0 + r] = hc + hbod[0];
    }
}

// ---------------------------------------------------------------------------
extern "C" void kernel_launch(void* const* d_in, const int* in_sizes, int n_in,
                              void* d_out, int out_size, void* d_ws, size_t ws_size,
                              hipStream_t stream)
{
    const float* x    = (const float*)d_in[0];
    const float* W0   = (const float*)d_in[1];
    const float* A0   = (const float*)d_in[2];
    const float* b0   = (const float*)d_in[3];
    const float* eta0 = (const float*)d_in[4];
    const float* g0   = (const float*)d_in[5];
    const float* be0  = (const float*)d_in[6];
    const float* W1   = (const float*)d_in[7];
    const float* A1   = (const float*)d_in[8];
    const float* b1   = (const float*)d_in[9];
    const float* eta1 = (const float*)d_in[10];
    const float* g1   = (const float*)d_in[11];
    const float* be1  = (const float*)d_in[12];
    const float* W2   = (const float*)d_in[13];
    const float* A2   = (const float*)d_in[14];
    const float* b2   = (const float*)d_in[15];
    const float* eta2 = (const float*)d_in[16];
    const float* g2   = (const float*)d_in[17];
    const float* be2  = (const float*)d_in[18];
    const float* hw   = (const float*)d_in[19];
    const float* hbod = (const float*)d_in[20];
    float* out = (float*)d_out;

    char* w = (char*)d_ws;
    unsigned short* hb  = (unsigned short*)(w + 0);          // 20971520
    unsigned short* Wb0 = (unsigned short*)(w + 20971520);   // 5242880
    unsigned short* Sb0 = (unsigned short*)(w + 26214400);   // 5242880
    float* Py   = (float*)(w + 31457280);                    // 8388608
    float* Pp   = (float*)(w + 39845888);                    // 8388608
    float* W1T  = (float*)(w + 48234496);                    // 131072
    float* S1T  = (float*)(w + 48365568);                    // 131072
    float* W2T  = (float*)(w + 48496640);                    // 32768
    float* S2T  = (float*)(w + 48529408);                    // 32768
    float* hnm  = (float*)(w + 48562176);                    // 4096
    // total = 48566272 bytes

    hipLaunchKernelGGL(fft_prep_kernel, dim3(3804), dim3(512), 0, stream,
                       x, hb, hnm, W0, A0, Wb0, Sb0, W1, A1, W2, A2, W1T, S1T, W2T, S2T);
    hipLaunchKernelGGL(gemm0_kernel, dim3(512), dim3(256), 0, stream, hb, Wb0, Sb0, Py, Pp);
    hipLaunchKernelGGL(combine_tail_kernel, dim3(512), dim3(256), 0, stream, Py, Pp, hnm,
                       b0, eta0, g0, be0, W1T, S1T, b1, eta1, g1, be1,
                       W2T, S2T, b2, eta2, g2, be2, hw, hbod, out);
}